// Round 1
// baseline (976.082 us; speedup 1.0000x reference)
//
#include <hip/hip_runtime.h>
#include <cstddef>

// Problem constants
namespace {
constexpr int B = 32, C = 256, H = 56, W = 56, K = 16;
constexpr int HW = H * W;            // 3136
constexpr int WT_ELEMS = C * 9 * K;  // 36864
constexpr float EPS = 1e-5f;

// d_ws layout (in float elements)
constexpr size_t OFF_W1T = 0;            // [C][9][K] = 36864
constexpr size_t OFF_W2T = 36864;        // [C][9][K] = 36864
constexpr size_t OFF_A1  = 73728;        // [C]
constexpr size_t OFF_D1  = 73984;        // [C]
constexpr size_t OFF_A2  = 74240;        // [C]
constexpr size_t OFF_D2  = 74496;        // [C]
constexpr size_t OFF_G1  = 74752;        // [C] (int)
constexpr size_t OFF_G2  = 75008;        // [C] (int)
constexpr size_t OFF_Z1  = 75264;        // [B][HW][K] = 1605632
}  // namespace

// ---------------------------------------------------------------------------
// Prep: transpose weights to [c][tap][k] (so the k-inner loop is one uniform
// 64B scalar load per (c,tap)) and fold BN+bias+labels into per-channel
// constants:  h_c = relu(A1[c]*z1[g1[c]] + D1[c]),
//             out_c = relu(A2[c]*z2[g2[c]] + D2[c] + x_c)
// ---------------------------------------------------------------------------
__global__ __launch_bounds__(256) void prep_kernel(
    const float* __restrict__ w1, const float* __restrict__ b1,
    const float* __restrict__ w2, const float* __restrict__ b2,
    const float* __restrict__ gamma1, const float* __restrict__ beta1,
    const float* __restrict__ mean1, const float* __restrict__ var1,
    const float* __restrict__ gamma2, const float* __restrict__ beta2,
    const float* __restrict__ mean2, const float* __restrict__ var2,
    const int* __restrict__ lab1, const int* __restrict__ lab2,
    float* __restrict__ ws) {
  int i = blockIdx.x * 256 + threadIdx.x;
  if (i < WT_ELEMS) {
    int k = i & (K - 1);
    int ct = i >> 4;           // c*9 + t
    int c = ct / 9;
    int t = ct - c * 9;
    ws[OFF_W1T + i] = w1[k * (C * 9) + c * 9 + t];
    ws[OFF_W2T + i] = w2[k * (C * 9) + c * 9 + t];
  }
  if (i < C) {
    int g1 = lab1[i];
    int g2 = lab2[i];
    float a1 = gamma1[i] / sqrtf(var1[i] + EPS);
    float a2 = gamma2[i] / sqrtf(var2[i] + EPS);
    ws[OFF_A1 + i] = a1;
    ws[OFF_D1 + i] = a1 * b1[g1] + beta1[i] - mean1[i] * a1;
    ws[OFF_A2 + i] = a2;
    ws[OFF_D2 + i] = a2 * b2[g2] + beta2[i] - mean2[i] * a2;
    ((int*)ws)[OFF_G1 + i] = g1;
    ((int*)ws)[OFF_G2 + i] = g2;
  }
}

// ---------------------------------------------------------------------------
// Conv1: z1[b, y, x, k] = sum_c sum_tap x[b,c,y+dy,x+dx] * w1t[c,tap,k]
// One thread per output pixel, 16 accumulators. Weight reads are wave-uniform.
// ---------------------------------------------------------------------------
__global__ __launch_bounds__(128) void conv1_kernel(
    const float* __restrict__ x, float* __restrict__ ws) {
  const float* __restrict__ w1t = ws + OFF_W1T;
  float* __restrict__ z1 = ws + OFF_Z1;

  int p = blockIdx.x * 128 + threadIdx.x;  // global pixel id, exact cover
  int b = p / HW;
  int r = p - b * HW;
  int yy = r / W;
  int xx = r - yy * W;

  int off[9];
  bool val[9];
#pragma unroll
  for (int t = 0; t < 9; ++t) {
    int y2 = yy + t / 3 - 1;
    int x2 = xx + (t % 3) - 1;
    off[t] = y2 * W + x2;
    val[t] = ((unsigned)y2 < (unsigned)H) && ((unsigned)x2 < (unsigned)W);
  }

  const float* xb = x + (size_t)b * C * HW;
  float acc[K];
#pragma unroll
  for (int k = 0; k < K; ++k) acc[k] = 0.f;

  for (int c = 0; c < C; ++c) {
    const float* xc = xb + c * HW;
    const float* wc = w1t + c * (9 * K);
    float xv[9];
#pragma unroll
    for (int t = 0; t < 9; ++t) xv[t] = val[t] ? xc[off[t]] : 0.f;
#pragma unroll
    for (int t = 0; t < 9; ++t) {
#pragma unroll
      for (int k = 0; k < K; ++k) acc[k] = fmaf(xv[t], wc[t * K + k], acc[k]);
    }
  }

  float* zp = z1 + (size_t)p * K;
#pragma unroll
  for (int k = 0; k < K; ++k) zp[k] = acc[k];
}

// ---------------------------------------------------------------------------
// Conv2 + BN2 + residual + relu, computing h on the fly from z1:
//   h(c, pix) = relu(A1[c] * z1[pix][g1[c]] + D1[c])      (0 outside image)
//   z2[k]     = sum_c sum_tap h(c, tap_pix) * w2t[c,tap,k]
//   out[c]    = relu(A2[c] * z2[g2[c]] + D2[c] + x[c])
// z2[g2[c]] is a runtime-index select -> round-trip through LDS (stride 17
// to avoid bank conflicts) instead of dynamic register indexing.
// ---------------------------------------------------------------------------
__global__ __launch_bounds__(128) void conv2_kernel(
    const float* __restrict__ x, const float* __restrict__ ws,
    float* __restrict__ out) {
  const float* __restrict__ w2t = ws + OFF_W2T;
  const float* __restrict__ A1 = ws + OFF_A1;
  const float* __restrict__ D1 = ws + OFF_D1;
  const float* __restrict__ A2 = ws + OFF_A2;
  const float* __restrict__ D2 = ws + OFF_D2;
  const int* __restrict__ G1 = (const int*)ws + OFF_G1;
  const int* __restrict__ G2 = (const int*)ws + OFF_G2;
  const float* __restrict__ z1 = ws + OFF_Z1;

  __shared__ float zs[128 * 17];

  int p = blockIdx.x * 128 + threadIdx.x;
  int b = p / HW;
  int r = p - b * HW;
  int yy = r / W;
  int xx = r - yy * W;

  int off[9];
  bool val[9];
#pragma unroll
  for (int t = 0; t < 9; ++t) {
    int y2 = yy + t / 3 - 1;
    int x2 = xx + (t % 3) - 1;
    off[t] = (y2 * W + x2) * K;
    val[t] = ((unsigned)y2 < (unsigned)H) && ((unsigned)x2 < (unsigned)W);
  }

  const float* zb = z1 + (size_t)b * HW * K;
  float acc[K];
#pragma unroll
  for (int k = 0; k < K; ++k) acc[k] = 0.f;

  for (int c = 0; c < C; ++c) {
    int g = G1[c];
    float a = A1[c];
    float d = D1[c];
    const float* wc = w2t + c * (9 * K);
    float hv[9];
#pragma unroll
    for (int t = 0; t < 9; ++t) {
      float h = 0.f;
      if (val[t]) {
        float s = zb[off[t] + g];
        h = fmaxf(fmaf(a, s, d), 0.f);
      }
      hv[t] = h;
    }
#pragma unroll
    for (int t = 0; t < 9; ++t) {
#pragma unroll
      for (int k = 0; k < K; ++k) acc[k] = fmaf(hv[t], wc[t * K + k], acc[k]);
    }
  }

#pragma unroll
  for (int k = 0; k < K; ++k) zs[threadIdx.x * 17 + k] = acc[k];

  const float* xb = x + (size_t)b * C * HW + r;
  float* ob = out + (size_t)b * C * HW + r;
  for (int c = 0; c < C; ++c) {
    float v = fmaf(A2[c], zs[threadIdx.x * 17 + G2[c]], D2[c]) + xb[(size_t)c * HW];
    ob[(size_t)c * HW] = fmaxf(v, 0.f);
  }
}

// ---------------------------------------------------------------------------
extern "C" void kernel_launch(void* const* d_in, const int* in_sizes, int n_in,
                              void* d_out, int out_size, void* d_ws,
                              size_t ws_size, hipStream_t stream) {
  const float* x = (const float*)d_in[0];
  const float* w1 = (const float*)d_in[1];
  const float* b1 = (const float*)d_in[2];
  const float* w2 = (const float*)d_in[3];
  const float* b2 = (const float*)d_in[4];
  const float* gamma1 = (const float*)d_in[5];
  const float* beta1 = (const float*)d_in[6];
  const float* mean1 = (const float*)d_in[7];
  const float* var1 = (const float*)d_in[8];
  const float* gamma2 = (const float*)d_in[9];
  const float* beta2 = (const float*)d_in[10];
  const float* mean2 = (const float*)d_in[11];
  const float* var2 = (const float*)d_in[12];
  const int* lab1 = (const int*)d_in[13];
  const int* lab2 = (const int*)d_in[14];

  float* ws = (float*)d_ws;
  float* out = (float*)d_out;

  // prep: 36864 transpose elems -> 144 blocks of 256
  prep_kernel<<<(WT_ELEMS + 255) / 256, 256, 0, stream>>>(
      w1, b1, w2, b2, gamma1, beta1, mean1, var1, gamma2, beta2, mean2, var2,
      lab1, lab2, ws);

  // one thread per pixel: B*HW = 100352 = 784 * 128 exactly
  int nblocks = (B * HW) / 128;
  conv1_kernel<<<nblocks, 128, 0, stream>>>(x, ws);
  conv2_kernel<<<nblocks, 128, 0, stream>>>(x, ws, out);
}

// Round 3
// 404.603 us; speedup vs baseline: 2.4124x; 2.4124x over previous
//
#include <hip/hip_runtime.h>
#include <cstddef>
#include <cstdint>

typedef short short8 __attribute__((ext_vector_type(8)));
typedef float f32x4 __attribute__((ext_vector_type(4)));

namespace {
constexpr int B = 32, C = 256, H = 56, W = 56, K = 16;
constexpr int HW = H * W;                 // 3136
constexpr int WP = 58, PP = 58 * 58;      // padded row width / padded pixels
constexpr float EPS = 1e-5f;

// d_ws byte offsets
constexpr size_t OFF_WF1 = 0;                      // 36864 bf16 (B-frag order)
constexpr size_t OFF_WF2 = 73728;                  // 36864 bf16
constexpr size_t OFF_A1 = 147456, OFF_D1 = 148480; // 256 f32 each
constexpr size_t OFF_A2 = 149504, OFF_D2 = 150528;
constexpr size_t OFF_G1 = 151552, OFF_G2 = 152576; // 256 i32 each
constexpr size_t OFF_XT = 153600;                  // bf16 [B][PP][C], zero border
constexpr size_t XT_BYTES = (size_t)B * PP * C * 2;
constexpr size_t OFF_HB = OFF_XT + XT_BYTES;       // bf16 [B][PP][C], zero border
// border zeroing work: 2 buffers * 32 imgs * 228 border pix * 32 uint4
constexpr int BORDER_U4 = 2 * 32 * 228 * 32;       // 466944 = 1824*256
}  // namespace

__device__ inline ushort f2bf(float f) {
  uint32_t u = __float_as_uint(f);
  u += 0x7fff + ((u >> 16) & 1);
  return (ushort)(u >> 16);
}

// ---------------------------------------------------------------------------
// prep: weight shuffle into MFMA B-fragment lane order, BN/bias/label folding,
// and zeroing the padded borders of xT and h (ws is re-poisoned every call).
// Wf[(t*8+cc)*64 + lane][j] = w[k=lane&15][c=cc*32+(lane>>4)*8+j][tap t]
// ---------------------------------------------------------------------------
__global__ __launch_bounds__(256) void prep_kernel(
    const float* __restrict__ w1, const float* __restrict__ b1,
    const float* __restrict__ w2, const float* __restrict__ b2,
    const float* __restrict__ gamma1, const float* __restrict__ beta1,
    const float* __restrict__ mean1, const float* __restrict__ var1,
    const float* __restrict__ gamma2, const float* __restrict__ beta2,
    const float* __restrict__ mean2, const float* __restrict__ var2,
    const int* __restrict__ lab1, const int* __restrict__ lab2,
    char* __restrict__ wsb) {
  int bid = blockIdx.x, tid = threadIdx.x;
  if (bid < 288) {
    int i = bid * 256 + tid;  // [0, 73728)
    int which = i >= 36864;
    int ii = which ? i - 36864 : i;
    int j = ii & 7, lane = (ii >> 3) & 63, cc = (ii >> 9) & 7, t = ii >> 12;
    int c = cc * 32 + ((lane >> 4) << 3) + j;
    int k = lane & 15;
    const float* w = which ? w2 : w1;
    ushort* wf = (ushort*)(wsb + (which ? OFF_WF2 : OFF_WF1));
    wf[ii] = f2bf(w[k * (C * 9) + c * 9 + t]);
    if (i < C) {
      int g1 = lab1[i], g2 = lab2[i];
      float a1 = gamma1[i] / sqrtf(var1[i] + EPS);
      float a2 = gamma2[i] / sqrtf(var2[i] + EPS);
      ((float*)(wsb + OFF_A1))[i] = a1;
      ((float*)(wsb + OFF_D1))[i] = a1 * b1[g1] + beta1[i] - mean1[i] * a1;
      ((float*)(wsb + OFF_A2))[i] = a2;
      ((float*)(wsb + OFF_D2))[i] = a2 * b2[g2] + beta2[i] - mean2[i] * a2;
      ((int*)(wsb + OFF_G1))[i] = g1;
      ((int*)(wsb + OFF_G2))[i] = g2;
    }
  } else {
    int idx = (bid - 288) * 256 + tid;
    if (idx < BORDER_U4) {
      int which = idx >= (BORDER_U4 / 2);
      int j = which ? idx - BORDER_U4 / 2 : idx;
      int pix = j >> 5, q = j & 31;  // 32 uint4 per padded pixel (256 bf16)
      int b = pix / 228, e = pix - b * 228;
      int y, x;
      if (e < 58) { y = 0; x = e; }
      else if (e < 116) { y = 57; x = e - 58; }
      else if (e < 172) { y = e - 115; x = 0; }
      else { y = e - 171; x = 57; }
      size_t off = ((size_t)b * PP + y * WP + x) * C * 2 + (size_t)q * 16;
      int4 z = {0, 0, 0, 0};
      *(int4*)(wsb + (which ? OFF_HB : OFF_XT) + off) = z;
    }
  }
}

// ---------------------------------------------------------------------------
// transpose: x[b][c][p] f32 -> xT[b][padded p][c] bf16 (interior only)
// ---------------------------------------------------------------------------
__global__ __launch_bounds__(256) void transpose_kernel(
    const float* __restrict__ x, char* __restrict__ wsb) {
  __shared__ float t[64][65];
  int bid = blockIdx.x;  // b*196 + pt*4 + ct
  int b = bid / 196, rem = bid - b * 196, pt = rem >> 2, ct = rem & 3;
  int p0 = pt * 64, c0 = ct * 64;
  int tid = threadIdx.x, lane = tid & 63, grp = tid >> 6;
  const float* xb = x + ((size_t)b * C + c0) * HW + p0;
#pragma unroll
  for (int r = 0; r < 16; ++r) {
    int row = r * 4 + grp;
    t[row][lane] = xb[(size_t)row * HW + lane];
  }
  __syncthreads();
  ushort* xt = (ushort*)(wsb + OFF_XT) + (size_t)b * PP * C;
  int c2 = (tid & 31) * 2, g = tid >> 5;
#pragma unroll
  for (int r = 0; r < 8; ++r) {
    int prow = r * 8 + g;
    int p = p0 + prow;
    int y = p / 56, xx = p - y * 56;
    uint v = (uint)f2bf(t[c2][prow]) | ((uint)f2bf(t[c2 + 1][prow]) << 16);
    *(uint*)(xt + ((size_t)(y + 1) * WP + xx + 1) * C + c0 + c2) = v;
  }
}

// ---------------------------------------------------------------------------
// conv1: z1 = im2col(xT) @ Wf1 via MFMA; epilogue expands to
//        h[p][c] = relu(A1[c]*z1[p][g1[c]] + D1[c]) bf16 (padded layout)
// Block: 256 thr = 4 waves; wave = 32 pixels (2 M-frags); grid covers 100352.
// ---------------------------------------------------------------------------
__global__ __launch_bounds__(256) void conv1_kernel(char* __restrict__ wsb) {
  __shared__ float zs[128 * 17];
  int tid = threadIdx.x, lane = tid & 63, wave = tid >> 6;
  int row = lane & 15, blk = lane >> 4;
  int gpb = blockIdx.x * 128 + wave * 32;
  const ushort* xt = (const ushort*)(wsb + OFF_XT);
  const ushort* wfl = (const ushort*)(wsb + OFF_WF1) + lane * 8;

  int gp0 = gpb + row, gp1 = gpb + 16 + row;
  int b0 = gp0 / HW, r0 = gp0 - b0 * HW, y0 = r0 / 56, x0 = r0 - y0 * 56;
  int b1_ = gp1 / HW, r1 = gp1 - b1_ * HW, y1 = r1 / 56, x1 = r1 - y1 * 56;
  const ushort* ap0 = xt + ((size_t)b0 * PP + (y0 + 1) * WP + (x0 + 1)) * C;
  const ushort* ap1 = xt + ((size_t)b1_ * PP + (y1 + 1) * WP + (x1 + 1)) * C;

  f32x4 acc0 = {0.f, 0.f, 0.f, 0.f}, acc1 = {0.f, 0.f, 0.f, 0.f};
#pragma unroll
  for (int t = 0; t < 9; ++t) {
    const int toff = ((t / 3 - 1) * WP + (t % 3 - 1)) * C;
#pragma unroll
    for (int cc = 0; cc < 8; ++cc) {
      short8 bf = *(const short8*)(wfl + (t * 8 + cc) * 512);
      int ko = toff + cc * 32 + blk * 8;
      short8 a0 = *(const short8*)(ap0 + ko);
      short8 a1 = *(const short8*)(ap1 + ko);
      acc0 = __builtin_amdgcn_mfma_f32_16x16x32_bf16(a0, bf, acc0, 0, 0, 0);
      acc1 = __builtin_amdgcn_mfma_f32_16x16x32_bf16(a1, bf, acc1, 0, 0, 0);
    }
  }
  // D-frag: col(lane&15)=centroid k, row(blk*4+i)=pixel-in-frag
#pragma unroll
  for (int i = 0; i < 4; ++i) {
    zs[(wave * 32 + blk * 4 + i) * 17 + row] = acc0[i];
    zs[(wave * 32 + 16 + blk * 4 + i) * 17 + row] = acc1[i];
  }
  __syncthreads();

  // expansion: wave's 32 pixels; lane covers c = lane*4 .. lane*4+3
  f32x4 a_ = *(const f32x4*)((const float*)(wsb + OFF_A1) + lane * 4);
  f32x4 d_ = *(const f32x4*)((const float*)(wsb + OFF_D1) + lane * 4);
  int4 g_ = *(const int4*)((const int*)(wsb + OFF_G1) + lane * 4);
  ushort* hb = (ushort*)(wsb + OFF_HB);
  for (int px = 0; px < 32; ++px) {
    int gp = gpb + px;
    int b = gp / HW, r = gp - b * HW, y = r / 56, xx = r - y * 56;
    const float* zr = zs + (wave * 32 + px) * 17;
    float h0 = fmaxf(fmaf(a_.x, zr[g_.x], d_.x), 0.f);
    float h1 = fmaxf(fmaf(a_.y, zr[g_.y], d_.y), 0.f);
    float h2 = fmaxf(fmaf(a_.z, zr[g_.z], d_.z), 0.f);
    float h3 = fmaxf(fmaf(a_.w, zr[g_.w], d_.w), 0.f);
    uint2 v;
    v.x = (uint)f2bf(h0) | ((uint)f2bf(h1) << 16);
    v.y = (uint)f2bf(h2) | ((uint)f2bf(h3) << 16);
    *(uint2*)(hb + ((size_t)b * PP + (y + 1) * WP + (xx + 1)) * C + lane * 4) = v;
  }
}

// ---------------------------------------------------------------------------
// conv2: z2 = im2col(h) @ Wf2; epilogue:
//        out[b][c][p] = relu(A2[c]*z2[p][g2[c]] + D2[c] + x[b][c][p]) f32
// ---------------------------------------------------------------------------
__global__ __launch_bounds__(256) void conv2_kernel(
    const float* __restrict__ x, char* __restrict__ wsb,
    float* __restrict__ out) {
  __shared__ float zs[128 * 17];
  int tid = threadIdx.x, lane = tid & 63, wave = tid >> 6;
  int row = lane & 15, blk = lane >> 4;
  int gpb = blockIdx.x * 128 + wave * 32;
  const ushort* hbuf = (const ushort*)(wsb + OFF_HB);
  const ushort* wfl = (const ushort*)(wsb + OFF_WF2) + lane * 8;

  int gp0 = gpb + row, gp1 = gpb + 16 + row;
  int b0 = gp0 / HW, r0 = gp0 - b0 * HW, y0 = r0 / 56, x0 = r0 - y0 * 56;
  int b1_ = gp1 / HW, r1 = gp1 - b1_ * HW, y1 = r1 / 56, x1 = r1 - y1 * 56;
  const ushort* ap0 = hbuf + ((size_t)b0 * PP + (y0 + 1) * WP + (x0 + 1)) * C;
  const ushort* ap1 = hbuf + ((size_t)b1_ * PP + (y1 + 1) * WP + (x1 + 1)) * C;

  f32x4 acc0 = {0.f, 0.f, 0.f, 0.f}, acc1 = {0.f, 0.f, 0.f, 0.f};
#pragma unroll
  for (int t = 0; t < 9; ++t) {
    const int toff = ((t / 3 - 1) * WP + (t % 3 - 1)) * C;
#pragma unroll
    for (int cc = 0; cc < 8; ++cc) {
      short8 bf = *(const short8*)(wfl + (t * 8 + cc) * 512);
      int ko = toff + cc * 32 + blk * 8;
      short8 a0 = *(const short8*)(ap0 + ko);
      short8 a1 = *(const short8*)(ap1 + ko);
      acc0 = __builtin_amdgcn_mfma_f32_16x16x32_bf16(a0, bf, acc0, 0, 0, 0);
      acc1 = __builtin_amdgcn_mfma_f32_16x16x32_bf16(a1, bf, acc1, 0, 0, 0);
    }
  }
#pragma unroll
  for (int i = 0; i < 4; ++i) {
    zs[(wave * 32 + blk * 4 + i) * 17 + row] = acc0[i];
    zs[(wave * 32 + 16 + blk * 4 + i) * 17 + row] = acc1[i];
  }
  __syncthreads();

  const float* A2p = (const float*)(wsb + OFF_A2);
  const float* D2p = (const float*)(wsb + OFF_D2);
  const int* G2p = (const int*)(wsb + OFF_G2);
  int pl = lane & 31, ch = lane >> 5;  // lanes 0-31: even c, 32-63: odd c
  int gp = gpb + pl;
  int b = gp / HW, r = gp - b * HW;
  const float* zrow = zs + (wave * 32 + pl) * 17;
  const float* xp = x + (size_t)b * C * HW + r;
  float* op = out + (size_t)b * C * HW + r;
#pragma unroll 4
  for (int cl = 0; cl < 128; ++cl) {
    int c = cl * 2 + ch;
    float a = A2p[c], dd = D2p[c];
    int g = G2p[c];
    float v = fmaf(a, zrow[g], dd) + xp[(size_t)c * HW];
    op[(size_t)c * HW] = fmaxf(v, 0.f);
  }
}

// ---------------------------------------------------------------------------
extern "C" void kernel_launch(void* const* d_in, const int* in_sizes, int n_in,
                              void* d_out, int out_size, void* d_ws,
                              size_t ws_size, hipStream_t stream) {
  const float* x = (const float*)d_in[0];
  const float* w1 = (const float*)d_in[1];
  const float* b1 = (const float*)d_in[2];
  const float* w2 = (const float*)d_in[3];
  const float* b2 = (const float*)d_in[4];
  const float* gamma1 = (const float*)d_in[5];
  const float* beta1 = (const float*)d_in[6];
  const float* mean1 = (const float*)d_in[7];
  const float* var1 = (const float*)d_in[8];
  const float* gamma2 = (const float*)d_in[9];
  const float* beta2 = (const float*)d_in[10];
  const float* mean2 = (const float*)d_in[11];
  const float* var2 = (const float*)d_in[12];
  const int* lab1 = (const int*)d_in[13];
  const int* lab2 = (const int*)d_in[14];
  char* wsb = (char*)d_ws;
  float* out = (float*)d_out;

  prep_kernel<<<288 + 1824, 256, 0, stream>>>(
      w1, b1, w2, b2, gamma1, beta1, mean1, var1, gamma2, beta2, mean2, var2,
      lab1, lab2, wsb);
  transpose_kernel<<<32 * 196, 256, 0, stream>>>(x, wsb);
  conv1_kernel<<<(B * HW) / 128, 256, 0, stream>>>(wsb);
  conv2_kernel<<<(B * HW) / 128, 256, 0, stream>>>(x, wsb, out);
}

// Round 6
// 363.500 us; speedup vs baseline: 2.6852x; 1.1131x over previous
//
#include <hip/hip_runtime.h>
#include <cstddef>
#include <cstdint>

typedef short short8 __attribute__((ext_vector_type(8)));
typedef float f32x4 __attribute__((ext_vector_type(4)));

namespace {
constexpr int B = 32, C = 256, H = 56, W = 56, K = 16;
constexpr int HW = H * W;             // 3136
constexpr int WP = 58, PP = 58 * 58;  // padded width / padded pixels
constexpr float EPS = 1e-5f;

// d_ws byte offsets
constexpr size_t OFF_WF1 = 0;          // 73728 B bf16 weights (B-frag order)
constexpr size_t OFF_WF2 = 73728;      // 73728 B
constexpr size_t OFF_A1 = 147456, OFF_D1 = 148480;  // 256 f32 each
constexpr size_t OFF_A2 = 149504, OFF_D2 = 150528;
constexpr size_t OFF_G1 = 151552, OFF_G2 = 152576;  // 256 i32 each
constexpr size_t OFF_XT = 153600;      // bf16 [B][PP][C], zero borders
constexpr size_t XT_BYTES = (size_t)B * PP * C * 2;           // 55115776
constexpr size_t OFF_Z1 = OFF_XT + XT_BYTES;                  // f32 [B][HW][16]
constexpr size_t OFF_Z2 = OFF_Z1 + (size_t)B * HW * 16 * 4;   // f32 [B][HW][16]
constexpr int BORDER_U4 = 32 * 228 * 32;  // xT border zero tasks (16B each)
}  // namespace

__device__ inline ushort f2bf(float f) {
  uint32_t u = __float_as_uint(f);
  u += 0x7fff + ((u >> 16) & 1);
  return (ushort)(u >> 16);
}

// ---------------------------------------------------------------------------
// prep: weight shuffle to MFMA B-frag lane order, BN/bias/label folding,
// zero xT borders. Wf[(t*8+cc)*64+lane][j] = w[k=lane&15][c=cc*32+(lane>>4)*8+j][t]
// ---------------------------------------------------------------------------
__global__ __launch_bounds__(256) void prep_kernel(
    const float* __restrict__ w1, const float* __restrict__ b1,
    const float* __restrict__ w2, const float* __restrict__ b2,
    const float* __restrict__ gamma1, const float* __restrict__ beta1,
    const float* __restrict__ mean1, const float* __restrict__ var1,
    const float* __restrict__ gamma2, const float* __restrict__ beta2,
    const float* __restrict__ mean2, const float* __restrict__ var2,
    const int* __restrict__ lab1, const int* __restrict__ lab2,
    char* __restrict__ wsb) {
  int bid = blockIdx.x, tid = threadIdx.x;
  if (bid < 288) {
    int i = bid * 256 + tid;  // [0, 73728)
    int which = i >= 36864;
    int ii = which ? i - 36864 : i;
    int j = ii & 7, lane = (ii >> 3) & 63, cc = (ii >> 9) & 7, t = ii >> 12;
    int c = cc * 32 + ((lane >> 4) << 3) + j;
    int k = lane & 15;
    const float* w = which ? w2 : w1;
    ushort* wf = (ushort*)(wsb + (which ? OFF_WF2 : OFF_WF1));
    wf[ii] = f2bf(w[k * (C * 9) + c * 9 + t]);
    if (i < C) {
      int g1 = lab1[i], g2 = lab2[i];
      float a1 = gamma1[i] / sqrtf(var1[i] + EPS);
      float a2 = gamma2[i] / sqrtf(var2[i] + EPS);
      ((float*)(wsb + OFF_A1))[i] = a1;
      ((float*)(wsb + OFF_D1))[i] = a1 * b1[g1] + beta1[i] - mean1[i] * a1;
      ((float*)(wsb + OFF_A2))[i] = a2;
      ((float*)(wsb + OFF_D2))[i] = a2 * b2[g2] + beta2[i] - mean2[i] * a2;
      ((int*)(wsb + OFF_G1))[i] = g1;
      ((int*)(wsb + OFF_G2))[i] = g2;
    }
  } else {
    int idx = (bid - 288) * 256 + tid;
    if (idx < BORDER_U4) {
      int pix = idx >> 5, q = idx & 31;  // 32 int4 per padded pixel (256 bf16)
      int b = pix / 228, e = pix - b * 228;
      int y, x;
      if (e < 58) { y = 0; x = e; }
      else if (e < 116) { y = 57; x = e - 58; }
      else if (e < 172) { y = e - 115; x = 0; }
      else { y = e - 171; x = 57; }
      size_t off = OFF_XT + ((size_t)b * PP + y * WP + x) * 512 + (size_t)q * 16;
      int4 z = {0, 0, 0, 0};
      *(int4*)(wsb + off) = z;
    }
  }
}

// ---------------------------------------------------------------------------
// transpose: x[b][c][p] f32 -> xT[b][padded p][c] bf16 (interior only)
// ---------------------------------------------------------------------------
__global__ __launch_bounds__(256) void transpose_kernel(
    const float* __restrict__ x, char* __restrict__ wsb) {
  __shared__ float t[64][65];
  int bid = blockIdx.x;  // b*196 + pt*4 + ct
  int b = bid / 196, rem = bid - b * 196, pt = rem >> 2, ct = rem & 3;
  int p0 = pt * 64, c0 = ct * 64;
  int tid = threadIdx.x, lane = tid & 63, grp = tid >> 6;
  const float* xb = x + ((size_t)b * C + c0) * HW + p0;
#pragma unroll
  for (int r = 0; r < 16; ++r) {
    int row = r * 4 + grp;
    t[row][lane] = xb[(size_t)row * HW + lane];
  }
  __syncthreads();
  ushort* xt = (ushort*)(wsb + OFF_XT) + (size_t)b * PP * C;
  int c2 = (tid & 31) * 2, g = tid >> 5;
#pragma unroll
  for (int r = 0; r < 8; ++r) {
    int prow = r * 8 + g;
    int p = p0 + prow;
    int y = p / 56, xx = p - y * 56;
    uint v = (uint)f2bf(t[c2][prow]) | ((uint)f2bf(t[c2 + 1][prow]) << 16);
    *(uint*)(xt + ((size_t)(y + 1) * WP + xx + 1) * C + c0 + c2) = v;
  }
}

// ---------------------------------------------------------------------------
// Shared MFMA helpers: block = 2 output rows (112 px) of one image.
// LDS chunk layout: [pi][128B of 64 channels], byte = pi*128 + (ofs ^ ((pi&7)<<4))
// ---------------------------------------------------------------------------
// conv1: xT -> z1 (f32 [b][p][16]); K-chunks staged from global xT.
__global__ __launch_bounds__(256, 2) void conv1_kernel(char* __restrict__ wsb) {
  __shared__ char sbuf[59392];  // buf0 @0, buf1 @29696; zs aliases buf0 at end
  const int tid = threadIdx.x, lane = tid & 63, wave = tid >> 6;
  const int row = lane & 15, blk = lane >> 4;
  int bid = blockIdx.x;
  int wg = (bid & 7) * 112 + (bid >> 3);  // XCD-chunked swizzle (896%8==0)
  int b = wg / 28, j = wg - b * 28;
  int y0 = 2 * j;
  const char* xtb = wsb + OFF_XT + (size_t)b * (PP * C * 2);
  const char* wf = wsb + OFF_WF1;

  // A-frag LDS addresses per [frag][tap][ks]
  int addrA[2][9][2];
#pragma unroll
  for (int f = 0; f < 2; ++f) {
    int fr = (f == 1) ? (wave + 4) : wave;
    if (fr > 6) fr = wave;  // wave3 f1 unused
    int op = fr * 16 + row;
    int oy = (op >= 56) ? 1 : 0;
    int pib = (oy + 1) * 58 + (op - oy * 56) + 1;
#pragma unroll
    for (int t = 0; t < 9; ++t) {
      int pi = pib + (t / 3 - 1) * 58 + (t % 3 - 1);
      int swz = (pi & 7) << 4;
      addrA[f][t][0] = pi * 128 + ((blk * 16) ^ swz);
      addrA[f][t][1] = pi * 128 + ((64 + blk * 16) ^ swz);
    }
  }
  f32x4 acc0 = {0.f, 0.f, 0.f, 0.f}, acc1 = {0.f, 0.f, 0.f, 0.f};

  auto fill = [&](int cc, char* buf) {
#pragma unroll
    for (int i = 0; i < 8; ++i) {
      int idx = i * 256 + tid;
      if (idx < 1856) {
        int pi = idx >> 3, sub = idx & 7;
        int r = pi / 58, xx = pi - r * 58;
        const char* src =
            xtb + (((size_t)(y0 + r) * 58 + xx) * 256 + cc * 64) * 2 + sub * 16;
        int4 v = *(const int4*)src;
        *(int4*)(buf + pi * 128 + ((sub * 16) ^ ((pi & 7) << 4))) = v;
      }
    }
  };
  auto mstep = [&](int cc, const char* buf) {
#pragma unroll
    for (int t = 0; t < 9; ++t) {
#pragma unroll
      for (int ks = 0; ks < 2; ++ks) {
        short8 bf =
            *(const short8*)(wf + ((t * 8 + cc * 2 + ks) * 64 + lane) * 16);
        short8 a0 = *(const short8*)(buf + addrA[0][t][ks]);
        acc0 = __builtin_amdgcn_mfma_f32_16x16x32_bf16(a0, bf, acc0, 0, 0, 0);
        if (wave < 3) {
          short8 a1 = *(const short8*)(buf + addrA[1][t][ks]);
          acc1 = __builtin_amdgcn_mfma_f32_16x16x32_bf16(a1, bf, acc1, 0, 0, 0);
        }
      }
    }
  };

  fill(0, sbuf);
  __syncthreads();
  for (int cc = 0; cc < 4; ++cc) {
    if (cc < 3) fill(cc + 1, sbuf + ((cc + 1) & 1) * 29696);
    mstep(cc, sbuf + (cc & 1) * 29696);
    __syncthreads();
  }
  // acc -> zs (stride 17) -> z1 global
  float* zs = (float*)sbuf;
#pragma unroll
  for (int i = 0; i < 4; ++i) {
    zs[(wave * 16 + blk * 4 + i) * 17 + row] = acc0[i];
    if (wave < 3) zs[((wave + 4) * 16 + blk * 4 + i) * 17 + row] = acc1[i];
  }
  __syncthreads();
  float* z1 = (float*)(wsb + OFF_Z1) + ((size_t)b * HW + y0 * 56) * 16;
#pragma unroll
  for (int i = 0; i < 2; ++i) {
    int id = i * 256 + tid;
    if (id < 448) {
      int px = id >> 2, q = id & 3;
      f32x4 v;
      v.x = zs[px * 17 + q * 4 + 0];
      v.y = zs[px * 17 + q * 4 + 1];
      v.z = zs[px * 17 + q * 4 + 2];
      v.w = zs[px * 17 + q * 4 + 3];
      *(f32x4*)(z1 + (size_t)id * 4) = v;
    }
  }
}

// conv2: z1 -> z2 (f32 [b][p][16]); h expanded per 64-c chunk into LDS.
__global__ __launch_bounds__(256, 2) void conv2_kernel(char* __restrict__ wsb) {
  __shared__ char sbuf[75168];  // buf0 @0, buf1 @29696, zt(f32[3944]) @59392
  const int tid = threadIdx.x, lane = tid & 63, wave = tid >> 6;
  const int row = lane & 15, blk = lane >> 4;
  int bid = blockIdx.x;
  int wg = (bid & 7) * 112 + (bid >> 3);
  int b = wg / 28, j = wg - b * 28;
  int y0 = 2 * j;
  const char* wf = wsb + OFF_WF2;
  float* zt = (float*)(sbuf + 59392);

  // zero zt then load valid z1 rows (4 tile rows, stride-17 padded layout)
#pragma unroll
  for (int i = 0; i < 16; ++i) {
    int id = i * 256 + tid;
    if (id < 3944) zt[id] = 0.f;
  }
  __syncthreads();
  const float* z1 = (const float*)(wsb + OFF_Z1) + (size_t)b * HW * 16;
#pragma unroll
  for (int i = 0; i < 4; ++i) {
    int id = i * 256 + tid;  // < 896 float4 tasks
    if (id < 896) {
      int r = id / 224, rem = id - r * 224, xx = rem >> 2, q = rem & 3;
      int yg = y0 - 1 + r;
      if (yg >= 0 && yg < 56) {
        f32x4 v = *(const f32x4*)(z1 + ((size_t)yg * 56 + xx) * 16 + q * 4);
        int base = (r * 58 + xx + 1) * 17 + q * 4;
        zt[base + 0] = v.x;
        zt[base + 1] = v.y;
        zt[base + 2] = v.z;
        zt[base + 3] = v.w;
      }
    }
  }

  int addrA[2][9][2];
#pragma unroll
  for (int f = 0; f < 2; ++f) {
    int fr = (f == 1) ? (wave + 4) : wave;
    if (fr > 6) fr = wave;
    int op = fr * 16 + row;
    int oy = (op >= 56) ? 1 : 0;
    int pib = (oy + 1) * 58 + (op - oy * 56) + 1;
#pragma unroll
    for (int t = 0; t < 9; ++t) {
      int pi = pib + (t / 3 - 1) * 58 + (t % 3 - 1);
      int swz = (pi & 7) << 4;
      addrA[f][t][0] = pi * 128 + ((blk * 16) ^ swz);
      addrA[f][t][1] = pi * 128 + ((64 + blk * 16) ^ swz);
    }
  }
  f32x4 acc0 = {0.f, 0.f, 0.f, 0.f}, acc1 = {0.f, 0.f, 0.f, 0.f};
  const int cp = tid & 31, pig = tid >> 5;
  const float* A1 = (const float*)(wsb + OFF_A1);
  const float* D1 = (const float*)(wsb + OFF_D1);
  const int* G1 = (const int*)(wsb + OFF_G1);

  auto expand = [&](int cc, char* buf) {
    int c = cc * 64 + cp * 2;
    float2 a = *(const float2*)(A1 + c);
    float2 dd = *(const float2*)(D1 + c);
    int2 g = *(const int2*)(G1 + c);
#pragma unroll 4
    for (int i = 0; i < 29; ++i) {
      int pi = pig + i * 8;
      float za = zt[pi * 17 + g.x], zb = zt[pi * 17 + g.y];
      float h0 = fmaxf(fmaf(a.x, za, dd.x), 0.f);
      float h1 = fmaxf(fmaf(a.y, zb, dd.y), 0.f);
      uint u = (uint)f2bf(h0) | ((uint)f2bf(h1) << 16);
      *(uint*)(buf + pi * 128 + ((cp * 4) ^ ((pi & 7) << 4))) = u;
    }
  };
  auto mstep = [&](int cc, const char* buf) {
#pragma unroll
    for (int t = 0; t < 9; ++t) {
#pragma unroll
      for (int ks = 0; ks < 2; ++ks) {
        short8 bf =
            *(const short8*)(wf + ((t * 8 + cc * 2 + ks) * 64 + lane) * 16);
        short8 a0 = *(const short8*)(buf + addrA[0][t][ks]);
        acc0 = __builtin_amdgcn_mfma_f32_16x16x32_bf16(a0, bf, acc0, 0, 0, 0);
        if (wave < 3) {
          short8 a1 = *(const short8*)(buf + addrA[1][t][ks]);
          acc1 = __builtin_amdgcn_mfma_f32_16x16x32_bf16(a1, bf, acc1, 0, 0, 0);
        }
      }
    }
  };

  __syncthreads();  // zt ready
  expand(0, sbuf);
  __syncthreads();
  for (int cc = 0; cc < 4; ++cc) {
    if (cc < 3) expand(cc + 1, sbuf + ((cc + 1) & 1) * 29696);
    mstep(cc, sbuf + (cc & 1) * 29696);
    __syncthreads();
  }
  float* zs = (float*)sbuf;
#pragma unroll
  for (int i = 0; i < 4; ++i) {
    zs[(wave * 16 + blk * 4 + i) * 17 + row] = acc0[i];
    if (wave < 3) zs[((wave + 4) * 16 + blk * 4 + i) * 17 + row] = acc1[i];
  }
  __syncthreads();
  float* z2 = (float*)(wsb + OFF_Z2) + ((size_t)b * HW + y0 * 56) * 16;
#pragma unroll
  for (int i = 0; i < 2; ++i) {
    int id = i * 256 + tid;
    if (id < 448) {
      int px = id >> 2, q = id & 3;
      f32x4 v;
      v.x = zs[px * 17 + q * 4 + 0];
      v.y = zs[px * 17 + q * 4 + 1];
      v.z = zs[px * 17 + q * 4 + 2];
      v.w = zs[px * 17 + q * 4 + 3];
      *(f32x4*)(z2 + (size_t)id * 4) = v;
    }
  }
}

// ---------------------------------------------------------------------------
// epilogue: out[b][c][p] = relu(A2[c]*z2[b][p][g2[c]] + D2[c] + x[b][c][p])
// Pure streaming, float4 both sides; z2 rows (7KB/block) L1-hot.
// ---------------------------------------------------------------------------
__global__ __launch_bounds__(256) void epilogue_kernel(
    const float* __restrict__ x, const char* __restrict__ wsb,
    float* __restrict__ out) {
  int bid = blockIdx.x;
  int wg = (bid & 7) * 112 + (bid >> 3);
  int b = wg / 28, j = wg - b * 28;
  int p0 = 2 * j * 56;
  int tid = threadIdx.x;
  int q = tid & 31, cg = tid >> 5;
  bool act = q < 28;
  const float* A2 = (const float*)(wsb + OFF_A2);
  const float* D2 = (const float*)(wsb + OFF_D2);
  const int* G2 = (const int*)(wsb + OFF_G2);
  const float* z2 = (const float*)(wsb + OFF_Z2) + ((size_t)b * HW + p0) * 16;
  size_t xb = (size_t)b * C * HW + p0 + q * 4;
#pragma unroll 4
  for (int i = 0; i < 32; ++i) {
    int c = i * 8 + cg;
    if (act) {
      float a = A2[c], d = D2[c];
      int g = G2[c];
      const float* zr = z2 + q * 64 + g;
      f32x4 xv = *(const f32x4*)(x + xb + (size_t)c * HW);
      f32x4 v;
      v.x = fmaxf(fmaf(a, zr[0], d) + xv.x, 0.f);
      v.y = fmaxf(fmaf(a, zr[16], d) + xv.y, 0.f);
      v.z = fmaxf(fmaf(a, zr[32], d) + xv.z, 0.f);
      v.w = fmaxf(fmaf(a, zr[48], d) + xv.w, 0.f);
      *(f32x4*)(out + xb + (size_t)c * HW) = v;
    }
  }
}

// ---------------------------------------------------------------------------
extern "C" void kernel_launch(void* const* d_in, const int* in_sizes, int n_in,
                              void* d_out, int out_size, void* d_ws,
                              size_t ws_size, hipStream_t stream) {
  const float* x = (const float*)d_in[0];
  const float* w1 = (const float*)d_in[1];
  const float* b1 = (const float*)d_in[2];
  const float* w2 = (const float*)d_in[3];
  const float* b2 = (const float*)d_in[4];
  const float* gamma1 = (const float*)d_in[5];
  const float* beta1 = (const float*)d_in[6];
  const float* mean1 = (const float*)d_in[7];
  const float* var1 = (const float*)d_in[8];
  const float* gamma2 = (const float*)d_in[9];
  const float* beta2 = (const float*)d_in[10];
  const float* mean2 = (const float*)d_in[11];
  const float* var2 = (const float*)d_in[12];
  const int* lab1 = (const int*)d_in[13];
  const int* lab2 = (const int*)d_in[14];
  char* wsb = (char*)d_ws;
  float* out = (float*)d_out;

  prep_kernel<<<288 + 912, 256, 0, stream>>>(
      w1, b1, w2, b2, gamma1, beta1, mean1, var1, gamma2, beta2, mean2, var2,
      lab1, lab2, wsb);
  transpose_kernel<<<32 * 196, 256, 0, stream>>>(x, wsb);
  conv1_kernel<<<896, 256, 0, stream>>>(wsb);
  conv2_kernel<<<896, 256, 0, stream>>>(wsb);
  epilogue_kernel<<<896, 256, 0, stream>>>(x, wsb, out);
}

// Round 8
// 327.884 us; speedup vs baseline: 2.9769x; 1.1086x over previous
//
#include <hip/hip_runtime.h>
#include <cstddef>
#include <cstdint>

typedef _Float16 half8 __attribute__((ext_vector_type(8)));
typedef float f32x4 __attribute__((ext_vector_type(4)));

namespace {
constexpr int B = 32, C = 256, H = 56, W = 56, K = 16;
constexpr int HW = H * W;             // 3136
constexpr int WP = 58, PP = 58 * 58;  // padded width / padded pixels
constexpr float EPS = 1e-5f;

// d_ws byte offsets
constexpr size_t OFF_WF1 = 0;          // 73728 B f16 weights (B-frag order)
constexpr size_t OFF_WF2 = 73728;      // 73728 B
constexpr size_t OFF_A1 = 147456, OFF_D1 = 148480;  // 256 f32 each
constexpr size_t OFF_A2 = 149504, OFF_D2 = 150528;
constexpr size_t OFF_G1 = 151552, OFF_G2 = 152576;  // 256 i32 each
constexpr size_t OFF_XT = 153600;      // f16 [B][PP][C], zero borders
constexpr size_t XT_BYTES = (size_t)B * PP * C * 2;           // 55115776
constexpr size_t OFF_Z1 = OFF_XT + XT_BYTES;                  // f32 [B][HW][16]
constexpr size_t OFF_Z2 = OFF_Z1 + (size_t)B * HW * 16 * 4;   // f32 [B][16][HW] (k-planes)
constexpr int BORDER_U4 = 32 * 228 * 32;  // xT border zero tasks (16B each)
}  // namespace

__device__ inline ushort f2h(float f) {
  _Float16 h = (_Float16)f;
  return __builtin_bit_cast(ushort, h);
}

// ---------------------------------------------------------------------------
// prep: weight shuffle to MFMA B-frag lane order (f16), BN/bias/label folding,
// zero xT borders. Wf[(t*8+cc)*64+lane][j] = w[k=lane&15][c=cc*32+(lane>>4)*8+j][t]
// ---------------------------------------------------------------------------
__global__ __launch_bounds__(256) void prep_kernel(
    const float* __restrict__ w1, const float* __restrict__ b1,
    const float* __restrict__ w2, const float* __restrict__ b2,
    const float* __restrict__ gamma1, const float* __restrict__ beta1,
    const float* __restrict__ mean1, const float* __restrict__ var1,
    const float* __restrict__ gamma2, const float* __restrict__ beta2,
    const float* __restrict__ mean2, const float* __restrict__ var2,
    const int* __restrict__ lab1, const int* __restrict__ lab2,
    char* __restrict__ wsb) {
  int bid = blockIdx.x, tid = threadIdx.x;
  if (bid < 288) {
    int i = bid * 256 + tid;  // [0, 73728)
    int which = i >= 36864;
    int ii = which ? i - 36864 : i;
    int j = ii & 7, lane = (ii >> 3) & 63, cc = (ii >> 9) & 7, t = ii >> 12;
    int c = cc * 32 + ((lane >> 4) << 3) + j;
    int k = lane & 15;
    const float* w = which ? w2 : w1;
    ushort* wf = (ushort*)(wsb + (which ? OFF_WF2 : OFF_WF1));
    wf[ii] = f2h(w[k * (C * 9) + c * 9 + t]);
    if (i < C) {
      int g1 = lab1[i], g2 = lab2[i];
      float a1 = gamma1[i] / sqrtf(var1[i] + EPS);
      float a2 = gamma2[i] / sqrtf(var2[i] + EPS);
      ((float*)(wsb + OFF_A1))[i] = a1;
      ((float*)(wsb + OFF_D1))[i] = a1 * b1[g1] + beta1[i] - mean1[i] * a1;
      ((float*)(wsb + OFF_A2))[i] = a2;
      ((float*)(wsb + OFF_D2))[i] = a2 * b2[g2] + beta2[i] - mean2[i] * a2;
      ((int*)(wsb + OFF_G1))[i] = g1;
      ((int*)(wsb + OFF_G2))[i] = g2;
    }
  } else {
    int idx = (bid - 288) * 256 + tid;
    if (idx < BORDER_U4) {
      int pix = idx >> 5, q = idx & 31;  // 32 int4 per padded pixel (256 f16)
      int b = pix / 228, e = pix - b * 228;
      int y, x;
      if (e < 58) { y = 0; x = e; }
      else if (e < 116) { y = 57; x = e - 58; }
      else if (e < 172) { y = e - 115; x = 0; }
      else { y = e - 171; x = 57; }
      size_t off = OFF_XT + ((size_t)b * PP + y * WP + x) * 512 + (size_t)q * 16;
      int4 z = {0, 0, 0, 0};
      *(int4*)(wsb + off) = z;
    }
  }
}

// ---------------------------------------------------------------------------
// transpose: x[b][c][p] f32 -> xT[b][padded p][c] f16 (interior only)
// ---------------------------------------------------------------------------
__global__ __launch_bounds__(256) void transpose_kernel(
    const float* __restrict__ x, char* __restrict__ wsb) {
  __shared__ float t[64][65];
  int bid = blockIdx.x;  // b*196 + pt*4 + ct
  int b = bid / 196, rem = bid - b * 196, pt = rem >> 2, ct = rem & 3;
  int p0 = pt * 64, c0 = ct * 64;
  int tid = threadIdx.x, lane = tid & 63, grp = tid >> 6;
  const float* xb = x + ((size_t)b * C + c0) * HW + p0;
#pragma unroll
  for (int r = 0; r < 16; ++r) {
    int row = r * 4 + grp;
    t[row][lane] = xb[(size_t)row * HW + lane];
  }
  __syncthreads();
  ushort* xt = (ushort*)(wsb + OFF_XT) + (size_t)b * PP * C;
  int c2 = (tid & 31) * 2, g = tid >> 5;
#pragma unroll
  for (int r = 0; r < 8; ++r) {
    int prow = r * 8 + g;
    int p = p0 + prow;
    int y = p / 56, xx = p - y * 56;
    uint v = (uint)f2h(t[c2][prow]) | ((uint)f2h(t[c2 + 1][prow]) << 16);
    *(uint*)(xt + ((size_t)(y + 1) * WP + xx + 1) * C + c0 + c2) = v;
  }
}

// ---------------------------------------------------------------------------
// Shared MFMA structure: block = 2 output rows (112 px) of one image.
// LDS chunk layout: [pi][128B of 64 channels], byte = pi*128 + (ofs ^ ((pi&7)<<4))
// ---------------------------------------------------------------------------
// conv1: xT -> z1 (f32 [b][p][16]); K-chunks staged from global xT.
__global__ __launch_bounds__(256, 2) void conv1_kernel(char* __restrict__ wsb) {
  __shared__ char sbuf[59392];  // buf0 @0, buf1 @29696; zs aliases buf0 at end
  const int tid = threadIdx.x, lane = tid & 63, wave = tid >> 6;
  const int row = lane & 15, blk = lane >> 4;
  int bid = blockIdx.x;
  int wg = (bid & 7) * 112 + (bid >> 3);  // XCD-chunked swizzle (896%8==0)
  int b = wg / 28, j = wg - b * 28;
  int y0 = 2 * j;
  const char* xtb = wsb + OFF_XT + (size_t)b * (PP * C * 2);
  const char* wf = wsb + OFF_WF1;

  // A-frag LDS addresses per [frag][tap][ks]
  int addrA[2][9][2];
#pragma unroll
  for (int f = 0; f < 2; ++f) {
    int fr = (f == 1) ? (wave + 4) : wave;
    if (fr > 6) fr = wave;  // wave3 f1 unused
    int op = fr * 16 + row;
    int oy = (op >= 56) ? 1 : 0;
    int pib = (oy + 1) * 58 + (op - oy * 56) + 1;
#pragma unroll
    for (int t = 0; t < 9; ++t) {
      int pi = pib + (t / 3 - 1) * 58 + (t % 3 - 1);
      int swz = (pi & 7) << 4;
      addrA[f][t][0] = pi * 128 + ((blk * 16) ^ swz);
      addrA[f][t][1] = pi * 128 + ((64 + blk * 16) ^ swz);
    }
  }
  f32x4 acc0 = {0.f, 0.f, 0.f, 0.f}, acc1 = {0.f, 0.f, 0.f, 0.f};

  auto fill = [&](int cc, char* buf) {
#pragma unroll
    for (int i = 0; i < 8; ++i) {
      int idx = i * 256 + tid;
      if (idx < 1856) {
        int pi = idx >> 3, sub = idx & 7;
        int r = pi / 58, xx = pi - r * 58;
        const char* src =
            xtb + (((size_t)(y0 + r) * 58 + xx) * 256 + cc * 64) * 2 + sub * 16;
        int4 v = *(const int4*)src;
        *(int4*)(buf + pi * 128 + ((sub * 16) ^ ((pi & 7) << 4))) = v;
      }
    }
  };
  auto mstep = [&](int cc, const char* buf) {
#pragma unroll
    for (int t = 0; t < 9; ++t) {
#pragma unroll
      for (int ks = 0; ks < 2; ++ks) {
        half8 bf =
            *(const half8*)(wf + ((t * 8 + cc * 2 + ks) * 64 + lane) * 16);
        half8 a0 = *(const half8*)(buf + addrA[0][t][ks]);
        acc0 = __builtin_amdgcn_mfma_f32_16x16x32_f16(a0, bf, acc0, 0, 0, 0);
        if (wave < 3) {
          half8 a1 = *(const half8*)(buf + addrA[1][t][ks]);
          acc1 = __builtin_amdgcn_mfma_f32_16x16x32_f16(a1, bf, acc1, 0, 0, 0);
        }
      }
    }
  };

  fill(0, sbuf);
  __syncthreads();
  for (int cc = 0; cc < 4; ++cc) {
    if (cc < 3) fill(cc + 1, sbuf + ((cc + 1) & 1) * 29696);
    mstep(cc, sbuf + (cc & 1) * 29696);
    __syncthreads();
  }
  // acc -> zs (stride 17) -> z1 global
  float* zs = (float*)sbuf;
#pragma unroll
  for (int i = 0; i < 4; ++i) {
    zs[(wave * 16 + blk * 4 + i) * 17 + row] = acc0[i];
    if (wave < 3) zs[((wave + 4) * 16 + blk * 4 + i) * 17 + row] = acc1[i];
  }
  __syncthreads();
  float* z1 = (float*)(wsb + OFF_Z1) + ((size_t)b * HW + y0 * 56) * 16;
#pragma unroll
  for (int i = 0; i < 2; ++i) {
    int id = i * 256 + tid;
    if (id < 448) {
      int px = id >> 2, q = id & 3;
      f32x4 v;
      v.x = zs[px * 17 + q * 4 + 0];
      v.y = zs[px * 17 + q * 4 + 1];
      v.z = zs[px * 17 + q * 4 + 2];
      v.w = zs[px * 17 + q * 4 + 3];
      *(f32x4*)(z1 + (size_t)id * 4) = v;
    }
  }
}

// conv2: z1 -> z2T (f32 [b][16][HW] k-planes); h expanded per 64-c chunk in LDS.
__global__ __launch_bounds__(256, 2) void conv2_kernel(char* __restrict__ wsb) {
  __shared__ char sbuf[75168];  // buf0 @0, buf1 @29696, zt(f32[3944]) @59392
  const int tid = threadIdx.x, lane = tid & 63, wave = tid >> 6;
  const int row = lane & 15, blk = lane >> 4;
  int bid = blockIdx.x;
  int wg = (bid & 7) * 112 + (bid >> 3);
  int b = wg / 28, j = wg - b * 28;
  int y0 = 2 * j;
  const char* wf = wsb + OFF_WF2;
  float* zt = (float*)(sbuf + 59392);

  // zero zt then load valid z1 rows (4 tile rows, stride-17 padded layout)
#pragma unroll
  for (int i = 0; i < 16; ++i) {
    int id = i * 256 + tid;
    if (id < 3944) zt[id] = 0.f;
  }
  __syncthreads();
  const float* z1 = (const float*)(wsb + OFF_Z1) + (size_t)b * HW * 16;
#pragma unroll
  for (int i = 0; i < 4; ++i) {
    int id = i * 256 + tid;  // < 896 float4 tasks
    if (id < 896) {
      int r = id / 224, rem = id - r * 224, xx = rem >> 2, q = rem & 3;
      int yg = y0 - 1 + r;
      if (yg >= 0 && yg < 56) {
        f32x4 v = *(const f32x4*)(z1 + ((size_t)yg * 56 + xx) * 16 + q * 4);
        int base = (r * 58 + xx + 1) * 17 + q * 4;
        zt[base + 0] = v.x;
        zt[base + 1] = v.y;
        zt[base + 2] = v.z;
        zt[base + 3] = v.w;
      }
    }
  }

  int addrA[2][9][2];
#pragma unroll
  for (int f = 0; f < 2; ++f) {
    int fr = (f == 1) ? (wave + 4) : wave;
    if (fr > 6) fr = wave;
    int op = fr * 16 + row;
    int oy = (op >= 56) ? 1 : 0;
    int pib = (oy + 1) * 58 + (op - oy * 56) + 1;
#pragma unroll
    for (int t = 0; t < 9; ++t) {
      int pi = pib + (t / 3 - 1) * 58 + (t % 3 - 1);
      int swz = (pi & 7) << 4;
      addrA[f][t][0] = pi * 128 + ((blk * 16) ^ swz);
      addrA[f][t][1] = pi * 128 + ((64 + blk * 16) ^ swz);
    }
  }
  f32x4 acc0 = {0.f, 0.f, 0.f, 0.f}, acc1 = {0.f, 0.f, 0.f, 0.f};
  const int cp = tid & 31, pig = tid >> 5;
  const float* A1 = (const float*)(wsb + OFF_A1);
  const float* D1 = (const float*)(wsb + OFF_D1);
  const int* G1 = (const int*)(wsb + OFF_G1);

  auto expand = [&](int cc, char* buf) {
    int c = cc * 64 + cp * 2;
    float2 a = *(const float2*)(A1 + c);
    float2 dd = *(const float2*)(D1 + c);
    int2 g = *(const int2*)(G1 + c);
#pragma unroll 4
    for (int i = 0; i < 29; ++i) {
      int pi = pig + i * 8;
      float za = zt[pi * 17 + g.x], zb = zt[pi * 17 + g.y];
      float h0 = fmaxf(fmaf(a.x, za, dd.x), 0.f);
      float h1 = fmaxf(fmaf(a.y, zb, dd.y), 0.f);
      uint u = (uint)f2h(h0) | ((uint)f2h(h1) << 16);
      *(uint*)(buf + pi * 128 + ((cp * 4) ^ ((pi & 7) << 4))) = u;
    }
  };
  auto mstep = [&](int cc, const char* buf) {
#pragma unroll
    for (int t = 0; t < 9; ++t) {
#pragma unroll
      for (int ks = 0; ks < 2; ++ks) {
        half8 bf =
            *(const half8*)(wf + ((t * 8 + cc * 2 + ks) * 64 + lane) * 16);
        half8 a0 = *(const half8*)(buf + addrA[0][t][ks]);
        acc0 = __builtin_amdgcn_mfma_f32_16x16x32_f16(a0, bf, acc0, 0, 0, 0);
        if (wave < 3) {
          half8 a1 = *(const half8*)(buf + addrA[1][t][ks]);
          acc1 = __builtin_amdgcn_mfma_f32_16x16x32_f16(a1, bf, acc1, 0, 0, 0);
        }
      }
    }
  };

  __syncthreads();  // zt ready
  expand(0, sbuf);
  __syncthreads();
  for (int cc = 0; cc < 4; ++cc) {
    if (cc < 3) expand(cc + 1, sbuf + ((cc + 1) & 1) * 29696);
    mstep(cc, sbuf + (cc & 1) * 29696);
    __syncthreads();
  }
  float* zs = (float*)sbuf;
#pragma unroll
  for (int i = 0; i < 4; ++i) {
    zs[(wave * 16 + blk * 4 + i) * 17 + row] = acc0[i];
    if (wave < 3) zs[((wave + 4) * 16 + blk * 4 + i) * 17 + row] = acc1[i];
  }
  __syncthreads();
  // write z2 as 16 k-planes: z2T[b][k][p], 28 float4 per plane-chunk
  float* z2 = (float*)(wsb + OFF_Z2);
#pragma unroll
  for (int i = 0; i < 2; ++i) {
    int id = i * 256 + tid;
    if (id < 448) {
      int k = id / 28, q = id - k * 28;
      f32x4 v;
      v.x = zs[(q * 4 + 0) * 17 + k];
      v.y = zs[(q * 4 + 1) * 17 + k];
      v.z = zs[(q * 4 + 2) * 17 + k];
      v.w = zs[(q * 4 + 3) * 17 + k];
      *(f32x4*)(z2 + ((size_t)(b * 16 + k) * HW + y0 * 56 + q * 4)) = v;
    }
  }
}

// ---------------------------------------------------------------------------
// epilogue: out[idx] = relu(A2[c]*z2T[b][g2[c]][p] + D2[c] + x[idx])
// Flat: one float4 per thread; x/out/z2T all coalesced 16B ops.
// ---------------------------------------------------------------------------
__global__ __launch_bounds__(256) void epilogue_kernel(
    const float* __restrict__ x, const char* __restrict__ wsb,
    float* __restrict__ out) {
  int idx = blockIdx.x * 256 + threadIdx.x;  // < 6422528 float4s
  int p4 = idx % 784;
  int t = idx / 784;
  int c = t & 255, b = t >> 8;
  float a = ((const float*)(wsb + OFF_A2))[c];
  float d = ((const float*)(wsb + OFF_D2))[c];
  int g = ((const int*)(wsb + OFF_G2))[c];
  const float* zp =
      (const float*)(wsb + OFF_Z2) + ((size_t)(b * 16 + g) * HW + p4 * 4);
  f32x4 z = *(const f32x4*)zp;
  f32x4 xv = *(const f32x4*)(x + (size_t)idx * 4);
  f32x4 v;
  v.x = fmaxf(fmaf(a, z.x, d) + xv.x, 0.f);
  v.y = fmaxf(fmaf(a, z.y, d) + xv.y, 0.f);
  v.z = fmaxf(fmaf(a, z.z, d) + xv.z, 0.f);
  v.w = fmaxf(fmaf(a, z.w, d) + xv.w, 0.f);
  *(f32x4*)(out + (size_t)idx * 4) = v;
}

// ---------------------------------------------------------------------------
extern "C" void kernel_launch(void* const* d_in, const int* in_sizes, int n_in,
                              void* d_out, int out_size, void* d_ws,
                              size_t ws_size, hipStream_t stream) {
  const float* x = (const float*)d_in[0];
  const float* w1 = (const float*)d_in[1];
  const float* b1 = (const float*)d_in[2];
  const float* w2 = (const float*)d_in[3];
  const float* b2 = (const float*)d_in[4];
  const float* gamma1 = (const float*)d_in[5];
  const float* beta1 = (const float*)d_in[6];
  const float* mean1 = (const float*)d_in[7];
  const float* var1 = (const float*)d_in[8];
  const float* gamma2 = (const float*)d_in[9];
  const float* beta2 = (const float*)d_in[10];
  const float* mean2 = (const float*)d_in[11];
  const float* var2 = (const float*)d_in[12];
  const int* lab1 = (const int*)d_in[13];
  const int* lab2 = (const int*)d_in[14];
  char* wsb = (char*)d_ws;
  float* out = (float*)d_out;

  prep_kernel<<<288 + 912, 256, 0, stream>>>(
      w1, b1, w2, b2, gamma1, beta1, mean1, var1, gamma2, beta2, mean2, var2,
      lab1, lab2, wsb);
  transpose_kernel<<<32 * 196, 256, 0, stream>>>(x, wsb);
  conv1_kernel<<<896, 256, 0, stream>>>(wsb);
  conv2_kernel<<<896, 256, 0, stream>>>(wsb);
  // B*C*HW/4 float4s = 6422528 = 25088 * 256
  epilogue_kernel<<<25088, 256, 0, stream>>>(x, wsb, out);
}